// Round 1
// baseline (1103.095 us; speedup 1.0000x reference)
//
#include <hip/hip_runtime.h>
#include <hip/hip_bf16.h>
#include <math.h>

#define B_TOTAL 262144
#define NHEADS  30
#define D1      128
#define D2      64
#define DH      32
#define BLK     256
#define NBLK_IN (B_TOTAL / BLK)            // 1024
#define MAX_BLOCKS (NBLK_IN + NHEADS)      // 1054 (worst-case padded blocks)

// ---------------- ws layout (bytes) ----------------
// [0,120)    counts[30]  u32
// [128,248)  starts[30]  u32  (padded slot starts, multiples of 256)
// [256,376)  cursors[30] u32
// [512, 512+MAX_BLOCKS*4)  block_head[MAX_BLOCKS] i32
// [8192, 8192+MAX_BLOCKS*BLK*4) perm i32   (~1.05 MB)

__device__ __forceinline__ int head_id(int nn, int ll, int mm) {
    return (nn - 1) * nn * (2 * nn - 1) / 6 + ll * ll + (mm + ll);
}

__device__ __forceinline__ float fast_tanh(float v) {
    float a = fabsf(v);
    float e = __expf(2.0f * a);            // v_exp path; inf-safe for large a
    float r = 1.0f - 2.0f / (e + 1.0f);
    return copysignf(r, v);
}

__global__ __launch_bounds__(BLK) void k_hist(const int* __restrict__ n,
                                              const int* __restrict__ l,
                                              const int* __restrict__ m,
                                              unsigned* __restrict__ counts) {
    __shared__ unsigned lh[NHEADS];
    int t = threadIdx.x;
    if (t < NHEADS) lh[t] = 0u;
    __syncthreads();
    int i = blockIdx.x * BLK + t;
    int hid = head_id(n[i], l[i], m[i]);
    atomicAdd(&lh[hid], 1u);
    __syncthreads();
    if (t < NHEADS) atomicAdd(&counts[t], lh[t]);
}

__global__ void k_scan(const unsigned* __restrict__ counts,
                       unsigned* __restrict__ starts,
                       int* __restrict__ block_head) {
    // single thread: 30 bins, <=1054 block_head writes
    unsigned total_blocks = 0;
    for (int h = 0; h < NHEADS; ++h) {
        starts[h] = total_blocks * BLK;
        unsigned nb = (counts[h] + BLK - 1) / BLK;
        for (unsigned b = 0; b < nb; ++b) block_head[total_blocks + b] = h;
        total_blocks += nb;
    }
    for (unsigned b = total_blocks; b < MAX_BLOCKS; ++b) block_head[b] = -1;
}

__global__ __launch_bounds__(BLK) void k_scatter(const int* __restrict__ n,
                                                 const int* __restrict__ l,
                                                 const int* __restrict__ m,
                                                 const unsigned* __restrict__ starts,
                                                 unsigned* __restrict__ cursors,
                                                 int* __restrict__ perm) {
    int i = blockIdx.x * BLK + threadIdx.x;
    int hid = head_id(n[i], l[i], m[i]);
    unsigned pos = starts[hid] + atomicAdd(&cursors[hid], 1u);
    perm[pos] = i;
}

__global__ __launch_bounds__(BLK) void k_main(
    const float* __restrict__ x,
    const float* __restrict__ W1, const float* __restrict__ b1,
    const float* __restrict__ W2, const float* __restrict__ b2,
    const float* __restrict__ HW1, const float* __restrict__ Hb1,
    const float* __restrict__ HW2, const float* __restrict__ Hb2,
    const int* __restrict__ block_head, const int* __restrict__ perm,
    float* __restrict__ out)
{
    int h = block_head[blockIdx.x];
    if (h < 0) return;                      // whole block uniform -> safe
    h = __builtin_amdgcn_readfirstlane(h);  // force SGPR (uniform weights)

    __shared__ float sW1[2 * D1];
    __shared__ float sb1[D1];
    __shared__ float sW2[D1 * D2];   // 32 KB
    __shared__ float sb2[D2];
    __shared__ float sHW1[D2 * DH];  // 8 KB (this block's head)
    __shared__ float sHb1[DH];
    __shared__ float sHW2[DH * 2];
    __shared__ float sHb2[2];

    int t = threadIdx.x;
    for (int i = t; i < 2 * D1; i += BLK)  sW1[i] = W1[i];
    for (int i = t; i < D1; i += BLK)      sb1[i] = b1[i];
    for (int i = t; i < D1 * D2; i += BLK) sW2[i] = W2[i];
    for (int i = t; i < D2; i += BLK)      sb2[i] = b2[i];
    for (int i = t; i < D2 * DH; i += BLK) sHW1[i] = HW1[h * D2 * DH + i];
    for (int i = t; i < DH; i += BLK)      sHb1[i] = Hb1[h * DH + i];
    for (int i = t; i < DH * 2; i += BLK)  sHW2[i] = HW2[h * DH * 2 + i];
    if (t < 2) sHb2[t] = Hb2[h * 2 + t];
    __syncthreads();

    int gi = perm[blockIdx.x * BLK + t];
    bool valid = gi >= 0;
    int gv = valid ? gi : 0;
    float x0 = x[gv * 2 + 0];
    float x1 = x[gv * 2 + 1];

    // layer 1 + layer 2 fused (strip-mine over j so h1 never materializes)
    float acc2[D2];
    #pragma unroll
    for (int j2 = 0; j2 < D2; ++j2) acc2[j2] = sb2[j2];

    for (int j = 0; j < D1; ++j) {
        float t1 = fast_tanh(fmaf(x1, sW1[D1 + j], fmaf(x0, sW1[j], sb1[j])));
        #pragma unroll
        for (int j2 = 0; j2 < D2; ++j2)
            acc2[j2] = fmaf(t1, sW2[j * D2 + j2], acc2[j2]);
    }

    float h2v[D2];
    #pragma unroll
    for (int j2 = 0; j2 < D2; ++j2) h2v[j2] = fast_tanh(acc2[j2]);

    // head layer 1: [64] -> [32]
    float acc3[DH];
    #pragma unroll
    for (int j = 0; j < DH; ++j) acc3[j] = sHb1[j];
    for (int k = 0; k < D2; ++k) {
        float hv = h2v[k];
        #pragma unroll
        for (int j = 0; j < DH; ++j)
            acc3[j] = fmaf(hv, sHW1[k * DH + j], acc3[j]);
    }

    // head layer 2: [32] -> [2]
    float o0 = sHb2[0], o1 = sHb2[1];
    #pragma unroll
    for (int j = 0; j < DH; ++j) {
        float z = fast_tanh(acc3[j]);
        o0 = fmaf(z, sHW2[j * 2 + 0], o0);
        o1 = fmaf(z, sHW2[j * 2 + 1], o1);
    }

    if (valid) {
        out[gv * 2 + 0] = o0;
        out[gv * 2 + 1] = o1;
    }
}

extern "C" void kernel_launch(void* const* d_in, const int* in_sizes, int n_in,
                              void* d_out, int out_size, void* d_ws, size_t ws_size,
                              hipStream_t stream) {
    const float* x   = (const float*)d_in[0];
    const int*   n   = (const int*)d_in[1];
    const int*   l   = (const int*)d_in[2];
    const int*   m   = (const int*)d_in[3];
    const float* W1  = (const float*)d_in[4];
    const float* b1  = (const float*)d_in[5];
    const float* W2  = (const float*)d_in[6];
    const float* b2  = (const float*)d_in[7];
    const float* HW1 = (const float*)d_in[8];
    const float* Hb1 = (const float*)d_in[9];
    const float* HW2 = (const float*)d_in[10];
    const float* Hb2 = (const float*)d_in[11];
    float* out = (float*)d_out;

    char* ws = (char*)d_ws;
    unsigned* counts  = (unsigned*)(ws + 0);
    unsigned* starts  = (unsigned*)(ws + 128);
    unsigned* cursors = (unsigned*)(ws + 256);
    int* block_head   = (int*)(ws + 512);
    int* perm         = (int*)(ws + 8192);

    hipMemsetAsync(ws, 0, 512, stream);                                  // counts/starts/cursors
    hipMemsetAsync(perm, 0xFF, (size_t)MAX_BLOCKS * BLK * sizeof(int), stream); // -1 sentinels

    k_hist   <<<NBLK_IN, BLK, 0, stream>>>(n, l, m, counts);
    k_scan   <<<1, 1, 0, stream>>>(counts, starts, block_head);
    k_scatter<<<NBLK_IN, BLK, 0, stream>>>(n, l, m, starts, cursors, perm);
    k_main   <<<MAX_BLOCKS, BLK, 0, stream>>>(x, W1, b1, W2, b2,
                                              HW1, Hb1, HW2, Hb2,
                                              block_head, perm, out);
}

// Round 2
// 184.089 us; speedup vs baseline: 5.9922x; 5.9922x over previous
//
#include <hip/hip_runtime.h>
#include <hip/hip_bf16.h>
#include <math.h>

#define B_TOTAL 262144
#define NHEADS  30
#define D1      128
#define D2      64
#define DH      32
#define BLK     256
#define NBLK_IN (B_TOTAL / BLK)            // 1024
#define MAX_BLOCKS (NBLK_IN + NHEADS)      // 1054 (worst-case padded blocks)

// ---------------- ws layout (bytes) ----------------
// [0,120)       counts[30]  u32           (memset 0)
// [128,248)     starts[30]  u32
// [512,4728)    block_head[MAX_BLOCKS] i32
// [8192,139264)   block_counts[NBLK_IN*32] u32   (fully written by k_hist)
// [139264,270336) block_off[NBLK_IN*32]   u32   (fully written by k_scan)
// [270336, +MAX_BLOCKS*BLK*4) perm i32    (memset 0xFF)

__device__ __forceinline__ int head_id(int nn, int ll, int mm) {
    return (nn - 1) * nn * (2 * nn - 1) / 6 + ll * ll + (mm + ll);
}

__device__ __forceinline__ float fast_tanh(float v) {
    float a = fabsf(v);
    float e = __expf(2.0f * a);            // v_exp path; inf-safe for large a
    float r = 1.0f - 2.0f / (e + 1.0f);
    return copysignf(r, v);
}

__global__ __launch_bounds__(BLK) void k_hist(const int* __restrict__ n,
                                              const int* __restrict__ l,
                                              const int* __restrict__ m,
                                              unsigned* __restrict__ counts,
                                              unsigned* __restrict__ block_counts) {
    __shared__ unsigned lh[NHEADS];
    int t = threadIdx.x;
    if (t < NHEADS) lh[t] = 0u;
    __syncthreads();
    int i = blockIdx.x * BLK + t;
    int hid = head_id(n[i], l[i], m[i]);
    atomicAdd(&lh[hid], 1u);
    __syncthreads();
    if (t < NHEADS) {
        block_counts[blockIdx.x * 32 + t] = lh[t];
        atomicAdd(&counts[t], lh[t]);
    }
}

// one block, 1024 threads = 16 waves; wave w scans heads w and w+16
__global__ __launch_bounds__(1024) void k_scan(const unsigned* __restrict__ counts,
                                               const unsigned* __restrict__ block_counts,
                                               unsigned* __restrict__ block_off,
                                               unsigned* __restrict__ starts,
                                               int* __restrict__ block_head) {
    int tid  = threadIdx.x;
    int wid  = tid >> 6;
    int lane = tid & 63;

    for (int h = wid; h < NHEADS; h += 16) {
        unsigned running = 0;
        for (int c = 0; c < NBLK_IN / 64; ++c) {      // 16 chunks of 64 blocks
            int b = c * 64 + lane;
            unsigned v = block_counts[b * 32 + h];
            unsigned s = v;
            #pragma unroll
            for (int d = 1; d < 64; d <<= 1) {
                unsigned u = __shfl_up(s, d, 64);
                if (lane >= d) s += u;
            }
            block_off[b * 32 + h] = running + s - v;   // exclusive within head
            running += __shfl(s, 63, 64);
        }
    }

    if (tid == 0) {   // independent of the scans above (uses only counts)
        unsigned total_blocks = 0;
        for (int h = 0; h < NHEADS; ++h) {
            starts[h] = total_blocks * BLK;
            unsigned nb = (counts[h] + BLK - 1) / BLK;
            for (unsigned b = 0; b < nb; ++b) block_head[total_blocks + b] = h;
            total_blocks += nb;
        }
        for (unsigned b = total_blocks; b < MAX_BLOCKS; ++b) block_head[b] = -1;
    }
}

__global__ __launch_bounds__(BLK) void k_scatter(const int* __restrict__ n,
                                                 const int* __restrict__ l,
                                                 const int* __restrict__ m,
                                                 const unsigned* __restrict__ starts,
                                                 const unsigned* __restrict__ block_off,
                                                 int* __restrict__ perm) {
    __shared__ unsigned lcur[NHEADS];
    int t = threadIdx.x;
    if (t < NHEADS) lcur[t] = 0u;
    __syncthreads();
    int i = blockIdx.x * BLK + t;
    int hid = head_id(n[i], l[i], m[i]);
    unsigned rank = atomicAdd(&lcur[hid], 1u);        // LDS atomic only
    unsigned pos = starts[hid] + block_off[blockIdx.x * 32 + hid] + rank;
    perm[pos] = i;
}

__global__ __launch_bounds__(BLK) void k_main(
    const float* __restrict__ x,
    const float* __restrict__ W1, const float* __restrict__ b1,
    const float* __restrict__ W2, const float* __restrict__ b2,
    const float* __restrict__ HW1, const float* __restrict__ Hb1,
    const float* __restrict__ HW2, const float* __restrict__ Hb2,
    const int* __restrict__ block_head, const int* __restrict__ perm,
    float* __restrict__ out)
{
    int h = block_head[blockIdx.x];
    if (h < 0) return;                      // whole block uniform -> safe
    h = __builtin_amdgcn_readfirstlane(h);  // force SGPR (uniform weight base)

    int t = threadIdx.x;
    int gi = perm[blockIdx.x * BLK + t];
    bool valid = gi >= 0;
    int gv = valid ? gi : 0;
    float x0 = x[gv * 2 + 0];
    float x1 = x[gv * 2 + 1];

    // layer 1 + layer 2 fused; all weight reads are wave-uniform -> s_load
    float acc2[D2];
    #pragma unroll
    for (int j2 = 0; j2 < D2; ++j2) acc2[j2] = b2[j2];

    for (int j = 0; j < D1; ++j) {
        float w0 = W1[j], w1 = W1[D1 + j], bb = b1[j];
        float t1 = fast_tanh(fmaf(x1, w1, fmaf(x0, w0, bb)));
        #pragma unroll
        for (int j2 = 0; j2 < D2; ++j2)
            acc2[j2] = fmaf(t1, W2[j * D2 + j2], acc2[j2]);
    }

    float h2v[D2];
    #pragma unroll
    for (int j2 = 0; j2 < D2; ++j2) h2v[j2] = fast_tanh(acc2[j2]);

    // head layer 1: [64] -> [32]
    const float* hw1 = HW1 + h * D2 * DH;
    float acc3[DH];
    #pragma unroll
    for (int j = 0; j < DH; ++j) acc3[j] = Hb1[h * DH + j];
    for (int k = 0; k < D2; ++k) {
        float hv = h2v[k];
        #pragma unroll
        for (int j = 0; j < DH; ++j)
            acc3[j] = fmaf(hv, hw1[k * DH + j], acc3[j]);
    }

    // head layer 2: [32] -> [2]
    const float* hw2 = HW2 + h * DH * 2;
    float o0 = Hb2[h * 2 + 0], o1 = Hb2[h * 2 + 1];
    #pragma unroll
    for (int j = 0; j < DH; ++j) {
        float z = fast_tanh(acc3[j]);
        o0 = fmaf(z, hw2[j * 2 + 0], o0);
        o1 = fmaf(z, hw2[j * 2 + 1], o1);
    }

    if (valid) {
        out[gv * 2 + 0] = o0;
        out[gv * 2 + 1] = o1;
    }
}

extern "C" void kernel_launch(void* const* d_in, const int* in_sizes, int n_in,
                              void* d_out, int out_size, void* d_ws, size_t ws_size,
                              hipStream_t stream) {
    const float* x   = (const float*)d_in[0];
    const int*   n   = (const int*)d_in[1];
    const int*   l   = (const int*)d_in[2];
    const int*   m   = (const int*)d_in[3];
    const float* W1  = (const float*)d_in[4];
    const float* b1  = (const float*)d_in[5];
    const float* W2  = (const float*)d_in[6];
    const float* b2  = (const float*)d_in[7];
    const float* HW1 = (const float*)d_in[8];
    const float* Hb1 = (const float*)d_in[9];
    const float* HW2 = (const float*)d_in[10];
    const float* Hb2 = (const float*)d_in[11];
    float* out = (float*)d_out;

    char* ws = (char*)d_ws;
    unsigned* counts       = (unsigned*)(ws + 0);
    unsigned* starts       = (unsigned*)(ws + 128);
    int*      block_head   = (int*)(ws + 512);
    unsigned* block_counts = (unsigned*)(ws + 8192);
    unsigned* block_off    = (unsigned*)(ws + 139264);
    int*      perm         = (int*)(ws + 270336);

    hipMemsetAsync(ws, 0, 128, stream);                                        // counts
    hipMemsetAsync(perm, 0xFF, (size_t)MAX_BLOCKS * BLK * sizeof(int), stream); // -1 sentinels

    k_hist   <<<NBLK_IN, BLK, 0, stream>>>(n, l, m, counts, block_counts);
    k_scan   <<<1, 1024, 0, stream>>>(counts, block_counts, block_off, starts, block_head);
    k_scatter<<<NBLK_IN, BLK, 0, stream>>>(n, l, m, starts, block_off, perm);
    k_main   <<<MAX_BLOCKS, BLK, 0, stream>>>(x, W1, b1, W2, b2,
                                              HW1, Hb1, HW2, Hb2,
                                              block_head, perm, out);
}

// Round 3
// 124.110 us; speedup vs baseline: 8.8880x; 1.4833x over previous
//
#include <hip/hip_runtime.h>
#include <hip/hip_bf16.h>
#include <math.h>

#define B_TOTAL 262144
#define NHEADS  30
#define D1      128
#define D2      64
#define DH      32
#define BLK     256
#define NBLK_IN (B_TOTAL / BLK)            // 1024
#define MAX_BLOCKS (NBLK_IN + NHEADS)      // 1054

typedef __attribute__((ext_vector_type(8))) __bf16 bf16x8;
typedef __attribute__((ext_vector_type(4))) float  f32x4;

// ---------------- ws layout (bytes) ----------------
// 0        counts[30] u32            (memset 0)
// 128      starts[30] u32
// 512      block_head[MAX_BLOCKS] i32
// 8192     block_counts[1024*32] u32
// 139264   block_off[1024*32] u32
// 270336   perm[MAX_BLOCKS*256] i32  (memset 0xFF)
// 1349632  inv[B_TOTAL] i32
// 2400256  temp[MAX_BLOCKS*256*2] f32
// 4558848  W2f  bf16[8192]           (fragment-ordered)
// 4575232  HW1f bf16[30*2048]        (fragment-ordered)

__device__ __forceinline__ int head_id(int nn, int ll, int mm) {
    return (nn - 1) * nn * (2 * nn - 1) / 6 + ll * ll + (mm + ll);
}

__device__ __forceinline__ float fast_tanh(float v) {
    float a = fabsf(v);
    float e = __expf(2.0f * a);
    float r = 1.0f - 2.0f / (e + 1.0f);
    return copysignf(r, v);
}

__global__ __launch_bounds__(BLK) void k_hist(const int* __restrict__ n,
                                              const int* __restrict__ l,
                                              const int* __restrict__ m,
                                              unsigned* __restrict__ counts,
                                              unsigned* __restrict__ block_counts) {
    __shared__ unsigned lh[NHEADS];
    int t = threadIdx.x;
    if (t < NHEADS) lh[t] = 0u;
    __syncthreads();
    int i = blockIdx.x * BLK + t;
    int hid = head_id(n[i], l[i], m[i]);
    atomicAdd(&lh[hid], 1u);
    __syncthreads();
    if (t < NHEADS) {
        block_counts[blockIdx.x * 32 + t] = lh[t];
        atomicAdd(&counts[t], lh[t]);
    }
}

__global__ __launch_bounds__(1024) void k_scan(const unsigned* __restrict__ counts,
                                               const unsigned* __restrict__ block_counts,
                                               unsigned* __restrict__ block_off,
                                               unsigned* __restrict__ starts,
                                               int* __restrict__ block_head) {
    int tid  = threadIdx.x;
    int wid  = tid >> 6;
    int lane = tid & 63;

    for (int h = wid; h < NHEADS; h += 16) {
        unsigned running = 0;
        for (int c = 0; c < NBLK_IN / 64; ++c) {
            int b = c * 64 + lane;
            unsigned v = block_counts[b * 32 + h];
            unsigned s = v;
            #pragma unroll
            for (int d = 1; d < 64; d <<= 1) {
                unsigned u = __shfl_up(s, d, 64);
                if (lane >= d) s += u;
            }
            block_off[b * 32 + h] = running + s - v;
            running += __shfl(s, 63, 64);
        }
    }

    if (tid == 0) {
        unsigned total_blocks = 0;
        for (int h = 0; h < NHEADS; ++h) {
            starts[h] = total_blocks * BLK;
            unsigned nb = (counts[h] + BLK - 1) / BLK;
            for (unsigned b = 0; b < nb; ++b) block_head[total_blocks + b] = h;
            total_blocks += nb;
        }
        for (unsigned b = total_blocks; b < MAX_BLOCKS; ++b) block_head[b] = -1;
    }
}

__global__ __launch_bounds__(BLK) void k_scatter(const int* __restrict__ n,
                                                 const int* __restrict__ l,
                                                 const int* __restrict__ m,
                                                 const unsigned* __restrict__ starts,
                                                 const unsigned* __restrict__ block_off,
                                                 int* __restrict__ perm,
                                                 int* __restrict__ inv) {
    __shared__ unsigned lcur[NHEADS];
    int t = threadIdx.x;
    if (t < NHEADS) lcur[t] = 0u;
    __syncthreads();
    int i = blockIdx.x * BLK + t;
    int hid = head_id(n[i], l[i], m[i]);
    unsigned rank = atomicAdd(&lcur[hid], 1u);
    unsigned pos = starts[hid] + block_off[blockIdx.x * 32 + hid] + rank;
    perm[pos] = i;
    inv[i] = (int)pos;
}

// one-time weight conversion into MFMA-fragment order (bf16)
__global__ __launch_bounds__(BLK) void k_conv(const float* __restrict__ W2,
                                              const float* __restrict__ HW1,
                                              __bf16* __restrict__ W2f,
                                              __bf16* __restrict__ HW1f) {
    int idx = blockIdx.x * BLK + threadIdx.x;
    if (idx < 8192) {
        int jj = idx & 7, lane = (idx >> 3) & 63, nt = (idx >> 9) & 3, kt = (idx >> 11) & 3;
        int k = kt * 32 + (lane >> 4) * 8 + jj;
        int c = nt * 16 + (lane & 15);
        W2f[idx] = (__bf16)W2[k * D2 + c];
    } else {
        int id2 = idx - 8192;             // < 61440
        int jj = id2 & 7, lane = (id2 >> 3) & 63;
        int nt2 = (id2 >> 9) & 1, kt2 = (id2 >> 10) & 1, h = id2 >> 11;
        int k = kt2 * 32 + (lane >> 4) * 8 + jj;
        int c = nt2 * 16 + (lane & 15);
        HW1f[h * 2048 + ((kt2 * 2 + nt2) * 64 + lane) * 8 + jj] =
            (__bf16)HW1[h * (D2 * DH) + k * DH + c];
    }
}

__global__ __launch_bounds__(BLK) void k_main(
    const float* __restrict__ x,
    const float* __restrict__ W1, const float* __restrict__ b1,
    const float* __restrict__ b2,
    const float* __restrict__ Hb1, const float* __restrict__ HW2,
    const float* __restrict__ Hb2,
    const __bf16* __restrict__ W2f, const __bf16* __restrict__ HW1f,
    const int* __restrict__ block_head, const int* __restrict__ perm,
    float* __restrict__ temp)
{
    int h = block_head[blockIdx.x];
    if (h < 0) return;
    h = __builtin_amdgcn_readfirstlane(h);

    __shared__ float  sW1[3 * D1];          // w0 | w1 | b1
    __shared__ __bf16 T[256 * 64];          // 32 KB; row = 128B = 8 chunks of 16B, XOR-swizzled

    int t = threadIdx.x;
    for (int i = t; i < 3 * D1; i += BLK) sW1[i] = (i < 2 * D1) ? W1[i] : b1[i - 2 * D1];
    __syncthreads();

    int lane = t & 63, wv = t >> 6;
    int kgrp = lane >> 4;                   // 0..3
    int lid  = lane & 15;
    int slot = blockIdx.x * BLK + t;
    int gi = perm[slot];
    float x0 = 0.f, x1 = 0.f;
    if (gi >= 0) { x0 = x[gi * 2]; x1 = x[gi * 2 + 1]; }

    // x for the 4 m-tiles this wave owns (rows wv*64 + tm*16 + lid)
    float xs0[4], xs1[4];
    #pragma unroll
    for (int tm = 0; tm < 4; ++tm) {
        int src = tm * 16 + lid;
        xs0[tm] = __shfl(x0, src, 64);
        xs1[tm] = __shfl(x1, src, 64);
    }

    // ---- layer 2 GEMM: [256x128]x[128x64], acc init = b2 ----
    f32x4 acc2[4][4];
    #pragma unroll
    for (int tm = 0; tm < 4; ++tm)
        #pragma unroll
        for (int nt = 0; nt < 4; ++nt) {
            float bv = b2[nt * 16 + lid];
            f32x4 c4 = {bv, bv, bv, bv};
            acc2[tm][nt] = c4;
        }

    #pragma unroll
    for (int kt = 0; kt < 4; ++kt) {
        int jb = kt * 32 + kgrp * 8;
        float w0[8], w1[8], bb[8];
        #pragma unroll
        for (int jj = 0; jj < 8; ++jj) {
            w0[jj] = sW1[jb + jj];
            w1[jj] = sW1[D1 + jb + jj];
            bb[jj] = sW1[2 * D1 + jb + jj];
        }
        bf16x8 a1[4];
        #pragma unroll
        for (int tm = 0; tm < 4; ++tm)
            #pragma unroll
            for (int jj = 0; jj < 8; ++jj) {
                float v = fast_tanh(fmaf(xs1[tm], w1[jj], fmaf(xs0[tm], w0[jj], bb[jj])));
                a1[tm][jj] = (__bf16)v;
            }
        #pragma unroll
        for (int nt = 0; nt < 4; ++nt) {
            bf16x8 bfr = *reinterpret_cast<const bf16x8*>(W2f + ((kt * 4 + nt) * 64 + lane) * 8);
            #pragma unroll
            for (int tm = 0; tm < 4; ++tm)
                acc2[tm][nt] = __builtin_amdgcn_mfma_f32_16x16x32_bf16(a1[tm], bfr, acc2[tm][nt], 0, 0, 0);
        }
    }

    // ---- h2 = tanh(acc2) -> T (bf16, swizzled); D-layout: col=lid, row=kgrp*4+reg ----
    #pragma unroll
    for (int tm = 0; tm < 4; ++tm)
        #pragma unroll
        for (int nt = 0; nt < 4; ++nt)
            #pragma unroll
            for (int rg = 0; rg < 4; ++rg) {
                int r = wv * 64 + tm * 16 + kgrp * 4 + rg;
                int c = nt * 16 + lid;
                int chunk = (c >> 3) ^ (r & 7);
                T[r * 64 + chunk * 8 + (c & 7)] = (__bf16)fast_tanh(acc2[tm][nt][rg]);
            }
    __syncthreads();

    // ---- head layer 1 GEMM: [256x64]x[64x32], acc init = Hb1 ----
    f32x4 acc3[4][2];
    #pragma unroll
    for (int tm = 0; tm < 4; ++tm)
        #pragma unroll
        for (int nt = 0; nt < 2; ++nt) {
            float bv = Hb1[h * DH + nt * 16 + lid];
            f32x4 c4 = {bv, bv, bv, bv};
            acc3[tm][nt] = c4;
        }
    #pragma unroll
    for (int kt = 0; kt < 2; ++kt) {
        bf16x8 a2[4];
        #pragma unroll
        for (int tm = 0; tm < 4; ++tm) {
            int r = wv * 64 + tm * 16 + lid;
            int chunk = (kt * 4 + kgrp) ^ (r & 7);
            a2[tm] = *reinterpret_cast<const bf16x8*>(&T[r * 64 + chunk * 8]);
        }
        #pragma unroll
        for (int nt = 0; nt < 2; ++nt) {
            bf16x8 bfr = *reinterpret_cast<const bf16x8*>(HW1f + h * 2048 + ((kt * 2 + nt) * 64 + lane) * 8);
            #pragma unroll
            for (int tm = 0; tm < 4; ++tm)
                acc3[tm][nt] = __builtin_amdgcn_mfma_f32_16x16x32_bf16(a2[tm], bfr, acc3[tm][nt], 0, 0, 0);
        }
    }
    __syncthreads();   // everyone done reading h2 from T before z overwrites it

    // ---- z = tanh(acc3) -> T rows (chunks 0..3 XOR-swizzled over 0..7) ----
    #pragma unroll
    for (int tm = 0; tm < 4; ++tm)
        #pragma unroll
        for (int nt = 0; nt < 2; ++nt)
            #pragma unroll
            for (int rg = 0; rg < 4; ++rg) {
                int r = wv * 64 + tm * 16 + kgrp * 4 + rg;
                int c = nt * 16 + lid;
                int chunk = (c >> 3) ^ (r & 7);
                T[r * 64 + chunk * 8 + (c & 7)] = (__bf16)fast_tanh(acc3[tm][nt][rg]);
            }
    __syncthreads();

    // ---- head layer 2 (VALU): out = z @ HW2[h] + Hb2[h] ----
    float zf[32];
    #pragma unroll
    for (int c8 = 0; c8 < 4; ++c8) {
        int chunk = c8 ^ (t & 7);
        bf16x8 zz = *reinterpret_cast<const bf16x8*>(&T[t * 64 + chunk * 8]);
        #pragma unroll
        for (int jj = 0; jj < 8; ++jj) zf[c8 * 8 + jj] = (float)zz[jj];
    }
    const float* hw2 = HW2 + h * DH * 2;
    float o0 = Hb2[h * 2], o1 = Hb2[h * 2 + 1];
    #pragma unroll
    for (int j = 0; j < DH; ++j) {
        o0 = fmaf(zf[j], hw2[2 * j], o0);
        o1 = fmaf(zf[j], hw2[2 * j + 1], o1);
    }
    temp[slot * 2]     = o0;
    temp[slot * 2 + 1] = o1;
}

__global__ __launch_bounds__(BLK) void k_unperm(const int* __restrict__ inv,
                                                const float* __restrict__ temp,
                                                float* __restrict__ out) {
    int i = blockIdx.x * BLK + threadIdx.x;
    int pos = inv[i];
    float2 v = reinterpret_cast<const float2*>(temp)[pos];
    reinterpret_cast<float2*>(out)[i] = v;
}

extern "C" void kernel_launch(void* const* d_in, const int* in_sizes, int n_in,
                              void* d_out, int out_size, void* d_ws, size_t ws_size,
                              hipStream_t stream) {
    const float* x   = (const float*)d_in[0];
    const int*   n   = (const int*)d_in[1];
    const int*   l   = (const int*)d_in[2];
    const int*   m   = (const int*)d_in[3];
    const float* W1  = (const float*)d_in[4];
    const float* b1  = (const float*)d_in[5];
    const float* W2  = (const float*)d_in[6];
    const float* b2  = (const float*)d_in[7];
    const float* HW1 = (const float*)d_in[8];
    const float* Hb1 = (const float*)d_in[9];
    const float* HW2 = (const float*)d_in[10];
    const float* Hb2 = (const float*)d_in[11];
    float* out = (float*)d_out;

    char* ws = (char*)d_ws;
    unsigned* counts       = (unsigned*)(ws + 0);
    unsigned* starts       = (unsigned*)(ws + 128);
    int*      block_head   = (int*)(ws + 512);
    unsigned* block_counts = (unsigned*)(ws + 8192);
    unsigned* block_off    = (unsigned*)(ws + 139264);
    int*      perm         = (int*)(ws + 270336);
    int*      inv          = (int*)(ws + 1349632);
    float*    temp         = (float*)(ws + 2400256);
    __bf16*   W2f          = (__bf16*)(ws + 4558848);
    __bf16*   HW1f         = (__bf16*)(ws + 4575232);

    hipMemsetAsync(ws, 0, 128, stream);
    hipMemsetAsync(perm, 0xFF, (size_t)MAX_BLOCKS * BLK * sizeof(int), stream);

    k_conv   <<<272, BLK, 0, stream>>>(W2, HW1, W2f, HW1f);
    k_hist   <<<NBLK_IN, BLK, 0, stream>>>(n, l, m, counts, block_counts);
    k_scan   <<<1, 1024, 0, stream>>>(counts, block_counts, block_off, starts, block_head);
    k_scatter<<<NBLK_IN, BLK, 0, stream>>>(n, l, m, starts, block_off, perm, inv);
    k_main   <<<MAX_BLOCKS, BLK, 0, stream>>>(x, W1, b1, b2, Hb1, HW2, Hb2,
                                              W2f, HW1f, block_head, perm, temp);
    k_unperm <<<NBLK_IN, BLK, 0, stream>>>(inv, temp, out);
}